// Round 5
// baseline (545.464 us; speedup 1.0000x reference)
//
#include <hip/hip_runtime.h>
#include <hip/hip_bf16.h>
#include <math.h>

#define BB 16
#define H1 14
#define W1 254
#define HPH 19
#define HPW2 264    // padded NHWC width (cols 0..263; data at 2..255)
#define NCAP 28448
#define FLATSZ 227584   // 64*14*254

typedef __attribute__((ext_vector_type(8))) short bf16x8;
typedef __attribute__((ext_vector_type(4))) float f32x4;

__device__ __forceinline__ ushort f2bf(float f) {
  __hip_bfloat16 h = __float2bfloat16(f);
  return *(ushort*)&h;
}

// ---------- weight prep: wb[co][tap*64+ci] bf16, w3t[c][co] fp32 ----------
__global__ __launch_bounds__(256) void prep_w(const float* __restrict__ w2, const float* __restrict__ w3,
                                              ushort* __restrict__ wb, float* __restrict__ w3t) {
  int idx = blockIdx.x * 256 + threadIdx.x;
  if (idx < 147456) {
    int co = idx / 2304; int rem = idx - co * 2304;
    int tap = rem >> 6; int ci = rem & 63;
    wb[idx] = f2bf(w2[(co * 64 + ci) * 36 + tap]);
  }
  if (idx < 8192) {
    int co = idx & 63; int c = idx >> 6;
    w3t[idx] = w3[co * 128 + c];
  }
}

// ---------- conv1: 1->64, 6x6, stride 2 -> compact fp32 hc[b][c][14][254] ----------
__global__ __launch_bounds__(256) void conv1_k(const float* __restrict__ x, const float* __restrict__ w1,
                                               const float* __restrict__ b1, float* __restrict__ hc) {
  const int i = blockIdx.x, b = blockIdx.y;
  __shared__ float xs[6 * 512];
  __shared__ float wsh[2304];
  __shared__ float bsh[64];
  const int t = threadIdx.x;
  for (int idx = t; idx < 6 * 512; idx += 256) {
    int r = idx >> 9, c = idx & 511;
    xs[idx] = x[((size_t)b * 32 + 2 * i + r) * 512 + c];
  }
  for (int idx = t; idx < 2304; idx += 256) wsh[idx] = w1[idx];
  if (t < 64) bsh[t] = b1[t];
  __syncthreads();
  if (t < 254) {
    for (int c = 0; c < 64; c++) {
      float acc = bsh[c];
#pragma unroll
      for (int p = 0; p < 6; p++)
#pragma unroll
        for (int q = 0; q < 6; q++)
          acc = fmaf(xs[p * 512 + 2 * t + q], wsh[c * 36 + p * 6 + q], acc);
      acc = fmaxf(acc, 0.f);
      hc[(((size_t)b * 64 + c) * H1 + i) * W1 + t] = acc;
    }
  }
}

// ---------- transpose hc (NCHW fp32) -> hpc (padded NHWC bf16) ----------
__global__ __launch_bounds__(256) void nhwc_k(const float* __restrict__ hc, ushort* __restrict__ hpc) {
  const int ct = blockIdx.x, i = blockIdx.y, b = blockIdx.z;
  const int c0 = ct * 64;
  __shared__ float ls[64 * 65];
  const int t = threadIdx.x;
  for (int idx = t; idx < 4096; idx += 256) {
    int ci = idx >> 6, cc = idx & 63;
    int c = c0 + cc;
    ls[ci * 65 + cc] = (c < W1) ? hc[(((size_t)b * 64 + ci) * H1 + i) * W1 + c] : 0.f;
  }
  __syncthreads();
  uint* outp = (uint*)hpc;
  for (int idx = t; idx < 2048; idx += 256) {
    int cc = idx >> 5, ci2 = idx & 31;
    int c = c0 + cc;
    if (c < W1) {
      float f0 = ls[(2 * ci2) * 65 + cc];
      float f1 = ls[(2 * ci2 + 1) * 65 + cc];
      uint pk = (uint)f2bf(f0) | ((uint)f2bf(f1) << 16);
      outp[(((size_t)b * HPH + 2 + i) * HPW2 + 2 + c) * 32 + ci2] = pk;
    }
  }
}

// ---------- conv2 implicit-GEMM bf16 MFMA (per-tap LDS double-buffer pipeline) ----------
__device__ __forceinline__ void stage_b(const ushort* __restrict__ wb, ushort* __restrict__ bbuf,
                                        int tap, int w, int l) {
#pragma unroll
  for (int r = 0; r < 2; r++) {
    int v = r * 256 + w * 64 + l;
    int co = v >> 3, s = v & 7;
    int g = s ^ (co & 7);                       // XOR swizzle: slot s holds k-group g
    const ushort* gp = wb + co * 2304 + tap * 64 + g * 8;
    ushort* lp = bbuf + (size_t)(r * 256 + w * 64) * 8;   // wave-uniform base; lane scatters +l*16B
    __builtin_amdgcn_global_load_lds((const uint*)gp, (uint*)lp, 16, 0, 0);
  }
}

__global__ __launch_bounds__(256, 1) void conv2_mfma(const ushort* __restrict__ hpc,
                                                     const ushort* __restrict__ wb,
                                                     const float* __restrict__ b2, float* __restrict__ y) {
  const int b = blockIdx.z, i = blockIdx.y, j0 = blockIdx.x * 128;
  const int t = threadIdx.x;
  const int w = t >> 6, l = t & 63;
  const int lr = l & 15, quad = l >> 4;

  __shared__ ushort bls[2][4096];   // [buf][co*64 + slot*8] bf16, swizzled

  f32x4 acc[2][4];
#pragma unroll
  for (int mt = 0; mt < 2; mt++)
#pragma unroll
    for (int nt = 0; nt < 4; nt++) acc[mt][nt] = (f32x4){0.f, 0.f, 0.f, 0.f};

  const ushort* abase = hpc + (((size_t)b * HPH + i) * HPW2 + (j0 + w * 32 + lr)) * 64 + quad * 8;

  bf16x8 a0[2][2], a1[2][2];   // [ch][mt] for current / next tap

#define ALOAD(dst, tap)                                                        \
  {                                                                            \
    const int p_ = (tap) / 6, q_ = (tap) % 6;                                  \
    const ushort* ap_ = abase + ((size_t)p_ * HPW2 + q_) * 64;                 \
    dst[0][0] = *(const bf16x8*)(ap_);                                         \
    dst[0][1] = *(const bf16x8*)(ap_ + 1024);                                  \
    dst[1][0] = *(const bf16x8*)(ap_ + 32);                                    \
    dst[1][1] = *(const bf16x8*)(ap_ + 32 + 1024);                             \
  }

#define COMPUTE(a, bp)                                                         \
  {                                                                            \
    _Pragma("unroll")                                                          \
    for (int ch = 0; ch < 2; ch++) {                                           \
      const int g2 = ch * 4 + quad;                                            \
      _Pragma("unroll")                                                        \
      for (int nt = 0; nt < 4; nt++) {                                         \
        const int co = nt * 16 + lr;                                           \
        bf16x8 bf = *(const bf16x8*)((bp) + co * 64 + ((g2 ^ (co & 7)) * 8));  \
        acc[0][nt] = __builtin_amdgcn_mfma_f32_16x16x32_bf16(a[ch][0], bf, acc[0][nt], 0, 0, 0); \
        acc[1][nt] = __builtin_amdgcn_mfma_f32_16x16x32_bf16(a[ch][1], bf, acc[1][nt], 0, 0, 0); \
      }                                                                        \
    }                                                                          \
  }

  stage_b(wb, &bls[0][0], 0, w, l);
  __syncthreads();                 // B(0) resident
  ALOAD(a0, 0);

  for (int tp = 0; tp < 36; tp += 2) {
    stage_b(wb, &bls[1][0], tp + 1, w, l);
    ALOAD(a1, tp + 1);
    COMPUTE(a0, &bls[0][0]);
    __syncthreads();
    if (tp + 2 < 36) {
      stage_b(wb, &bls[0][0], tp + 2, w, l);
      ALOAD(a0, tp + 2);
    }
    COMPUTE(a1, &bls[1][0]);
    __syncthreads();
  }

#pragma unroll
  for (int nt = 0; nt < 4; nt++) {
    const int co = nt * 16 + lr;
    const float bias = b2[co];
    float* yrow = y + (((size_t)b * 64 + co) * H1 + i) * W1;
#pragma unroll
    for (int mt = 0; mt < 2; mt++) {
      const int jb = j0 + w * 32 + mt * 16 + quad * 4;
#pragma unroll
      for (int r = 0; r < 4; r++) {
        int j = jb + r;
        if (j < W1) yrow[j] = fmaxf(acc[mt][nt][r] + bias, 0.f);
      }
    }
  }
#undef ALOAD
#undef COMPUTE
}

// ---------- conv3: 1x1, 128->64, over concat(hc, y); NO relu ----------
__global__ __launch_bounds__(256) void conv3_k(const float* __restrict__ hc, const float* __restrict__ y,
                                               const float* __restrict__ w3t, const float* __restrict__ b3,
                                               float* __restrict__ out3) {
  const int b = blockIdx.z, i = blockIdx.y, j0 = blockIdx.x * 64;
  __shared__ float cs[32][64];
  __shared__ float wsh[32][64];
  const int t = threadIdx.x;
  const int cog = t >> 4, jg = t & 15;
  float acc[4][4];
#pragma unroll
  for (int a = 0; a < 4; a++)
#pragma unroll
    for (int j = 0; j < 4; j++) acc[a][j] = 0.f;

  for (int ch = 0; ch < 4; ch++) {
    __syncthreads();
    for (int idx = t; idx < 2048; idx += 256) {
      int cl = idx >> 6; int j = j0 + (idx & 63);
      int c = ch * 32 + cl;
      float v = 0.f;
      if (j < W1) {
        if (c < 64) v = hc[(((size_t)b * 64 + c) * H1 + i) * W1 + j];
        else        v = y[(((size_t)b * 64 + (c - 64)) * H1 + i) * W1 + j];
      }
      cs[cl][idx & 63] = v;
    }
    for (int idx = t; idx < 2048; idx += 256)
      wsh[idx >> 6][idx & 63] = w3t[(ch * 32 + (idx >> 6)) * 64 + (idx & 63)];
    __syncthreads();
#pragma unroll
    for (int c = 0; c < 32; c++) {
      float4 xv = *(const float4*)&cs[c][jg * 4];
      float4 wv = *(const float4*)&wsh[c][cog * 4];
#pragma unroll
      for (int jj = 0; jj < 4; jj++) {
        float xx = (&xv.x)[jj];
        acc[0][jj] = fmaf(wv.x, xx, acc[0][jj]);
        acc[1][jj] = fmaf(wv.y, xx, acc[1][jj]);
        acc[2][jj] = fmaf(wv.z, xx, acc[2][jj]);
        acc[3][jj] = fmaf(wv.w, xx, acc[3][jj]);
      }
    }
  }
#pragma unroll
  for (int a = 0; a < 4; a++) {
    int co = cog * 4 + a;
    float bias = b3[co];
#pragma unroll
    for (int jj = 0; jj < 4; jj++) {
      int j = j0 + jg * 4 + jj;
      if (j < W1) out3[(((size_t)b * 64 + co) * H1 + i) * W1 + j] = acc[a][jj] + bias;
    }
  }
}

// ---------- pc: per-capsule 8x8 transform ----------
__global__ __launch_bounds__(256) void pc_k(const float* __restrict__ out3, const float* __restrict__ pcw,
                                            const float* __restrict__ pcb, float* __restrict__ u) {
  int n = blockIdx.x * 256 + threadIdx.x;
  if (n >= NCAP) return;
  float pw[64];
  const float4* pwp = (const float4*)(pcw + (size_t)n * 64);
#pragma unroll
  for (int k = 0; k < 16; k++) {
    float4 v = pwp[k];
    pw[4 * k] = v.x; pw[4 * k + 1] = v.y; pw[4 * k + 2] = v.z; pw[4 * k + 3] = v.w;
  }
  float pb[8];
  {
    const float4* pbp = (const float4*)(pcb + (size_t)n * 8);
    float4 a = pbp[0], b = pbp[1];
    pb[0] = a.x; pb[1] = a.y; pb[2] = a.z; pb[3] = a.w;
    pb[4] = b.x; pb[5] = b.y; pb[6] = b.z; pb[7] = b.w;
  }
  for (int b = 0; b < BB; b++) {
    const float4* uip = (const float4*)(out3 + (size_t)b * FLATSZ + (size_t)n * 8);
    float4 a = uip[0], c = uip[1];
    float ui[8] = {a.x, a.y, a.z, a.w, c.x, c.y, c.z, c.w};
    float uo[8];
#pragma unroll
    for (int o = 0; o < 8; o++) uo[o] = pb[o];
#pragma unroll
    for (int i2 = 0; i2 < 8; i2++)
#pragma unroll
      for (int o = 0; o < 8; o++) uo[o] = fmaf(ui[i2], pw[i2 * 8 + o], uo[o]);
    float4* up = (float4*)(u + ((size_t)b * NCAP + n) * 8);
    up[0] = make_float4(uo[0], uo[1], uo[2], uo[3]);
    up[1] = make_float4(uo[4], uo[5], uo[6], uo[7]);
  }
}

// ---------- routing ----------
// lane l <-> (e = l>>3, o-pair o0 = 2*(l&7)); ec_w[n] coalesced: lane l holds floats [16l,16l+16).
// Block = 4 waves x 8 n = 32 capsules; grid 889 (= 28448/32 exact).
__device__ __forceinline__ void block_reduce_atomic(float* __restrict__ sg, const float sacc[32], int t, int l, int wv) {
  __shared__ float red[8192];
#pragma unroll
  for (int k = 0; k < 32; k++) red[k * 256 + wv * 64 + l] = sacc[k];
  __syncthreads();
#pragma unroll
  for (int m = 0; m < 8; m++) {
    int slot = t + 256 * m;                       // slot = b*128 + e*16 + o
    int b = slot >> 7, eo = slot & 127;
    int k = 2 * b + (eo & 1), l2 = eo >> 1;
    const float* r = red + k * 256 + l2;
    atomicAdd(&sg[slot], r[0] + r[64] + r[128] + r[192]);
  }
}

// r0: s0 = sum_n ec[n] . u[b,n]   (softmax over zero logits is uniform; 1/8 folded in squash)
__global__ __launch_bounds__(256, 4) void r0_k(const float* __restrict__ u, const float* __restrict__ ecw,
                                               float* __restrict__ s0) {
  const int t = threadIdx.x, l = t & 63, wv = t >> 6;
  const int nbase = blockIdx.x * 32 + wv * 8;
  float sacc[32];
#pragma unroll
  for (int k = 0; k < 32; k++) sacc[k] = 0.f;
  for (int c = 0; c < 8; c++) {
    const int n = nbase + c;
    const float4* ep = (const float4*)(ecw + (size_t)n * 1024 + l * 16);
    float4 e0 = ep[0], e1 = ep[1], e2 = ep[2], e3 = ep[3];
    float ec[16] = {e0.x, e0.y, e0.z, e0.w, e1.x, e1.y, e1.z, e1.w,
                    e2.x, e2.y, e2.z, e2.w, e3.x, e3.y, e3.z, e3.w};
#pragma unroll
    for (int half = 0; half < 2; half++) {
      float4 ua[8][2];   // 8 batches of u loads in flight
#pragma unroll
      for (int bb = 0; bb < 8; bb++) {
        const float4* up = (const float4*)(u + ((size_t)(half * 8 + bb) * NCAP + n) * 8);
        ua[bb][0] = up[0]; ua[bb][1] = up[1];
      }
#pragma unroll
      for (int bb = 0; bb < 8; bb++) {
        const int b = half * 8 + bb;
        float uv[8] = {ua[bb][0].x, ua[bb][0].y, ua[bb][0].z, ua[bb][0].w,
                       ua[bb][1].x, ua[bb][1].y, ua[bb][1].z, ua[bb][1].w};
        float h0 = 0.f, h1 = 0.f;
#pragma unroll
        for (int k = 0; k < 8; k++) { h0 = fmaf(ec[k], uv[k], h0); h1 = fmaf(ec[8 + k], uv[k], h1); }
        sacc[2 * b] += h0; sacc[2 * b + 1] += h1;
      }
    }
  }
  block_reduce_atomic(s0, sacc, t, l, wv);
}

// One refinement pass. b_log is linear in v, so pass 2 uses v = v0+v1 (no b_log storage).
__global__ __launch_bounds__(256, 4) void rr_k(const float* __restrict__ u, const float* __restrict__ ecw,
                                               const float* __restrict__ v, float* __restrict__ sout) {
  __shared__ float vlds[2048];
  const int t = threadIdx.x, l = t & 63, wv = t >> 6;
  for (int idx = t; idx < 2048; idx += 256) vlds[idx] = v[idx];
  __syncthreads();
  const int nbase = blockIdx.x * 32 + wv * 8;
  float sacc[32];
#pragma unroll
  for (int k = 0; k < 32; k++) sacc[k] = 0.f;
  for (int c = 0; c < 8; c++) {
    const int n = nbase + c;
    const float4* ep = (const float4*)(ecw + (size_t)n * 1024 + l * 16);
    float4 e0 = ep[0], e1 = ep[1], e2 = ep[2], e3 = ep[3];
    float ec[16] = {e0.x, e0.y, e0.z, e0.w, e1.x, e1.y, e1.z, e1.w,
                    e2.x, e2.y, e2.z, e2.w, e3.x, e3.y, e3.z, e3.w};
#pragma unroll
    for (int qb = 0; qb < 4; qb++) {
      float4 ua[4][2];   // 4-b batch of u loads in flight
#pragma unroll
      for (int bb = 0; bb < 4; bb++) {
        const float4* up = (const float4*)(u + ((size_t)(qb * 4 + bb) * NCAP + n) * 8);
        ua[bb][0] = up[0]; ua[bb][1] = up[1];
      }
      float uh0[4], uh1[4];
#pragma unroll
      for (int bb = 0; bb < 4; bb++) {
        float uv[8] = {ua[bb][0].x, ua[bb][0].y, ua[bb][0].z, ua[bb][0].w,
                       ua[bb][1].x, ua[bb][1].y, ua[bb][1].z, ua[bb][1].w};
        float h0 = 0.f, h1 = 0.f;
#pragma unroll
        for (int k = 0; k < 8; k++) { h0 = fmaf(ec[k], uv[k], h0); h1 = fmaf(ec[8 + k], uv[k], h1); }
        uh0[bb] = h0; uh1[bb] = h1;
      }
#pragma unroll
      for (int bb = 0; bb < 4; bb++) {
        const int b = qb * 4 + bb;
        float2 vv = *(const float2*)&vlds[b * 128 + 2 * l];
        float p = uh0[bb] * vv.x + uh1[bb] * vv.y;
        p += __shfl_xor(p, 1); p += __shfl_xor(p, 2); p += __shfl_xor(p, 4);   // dot over o
        float m = p;
        m = fmaxf(m, __shfl_xor(m, 8)); m = fmaxf(m, __shfl_xor(m, 16)); m = fmaxf(m, __shfl_xor(m, 32));
        float ex = __expf(p - m);
        float den = ex;
        den += __shfl_xor(den, 8); den += __shfl_xor(den, 16); den += __shfl_xor(den, 32);
        float cc = ex * __builtin_amdgcn_rcpf(den);
        sacc[2 * b] = fmaf(cc, uh0[bb], sacc[2 * b]);
        sacc[2 * b + 1] = fmaf(cc, uh1[bb], sacc[2 * b + 1]);
      }
    }
  }
  block_reduce_atomic(sout, sacc, t, l, wv);
}

// ---------- squash: vout = (vprev? vprev : 0) + squash(s*scale) ----------
__global__ void squash_k(const float* __restrict__ s, float scale, const float* __restrict__ vprev,
                         float* __restrict__ vout) {
  int t = threadIdx.x;   // 128 threads: (b,e)
  const float* sp = s + t * 16;
  float sv[16]; float nn = 0.f;
#pragma unroll
  for (int o = 0; o < 16; o++) { float x = sp[o] * scale; sv[o] = x; nn = fmaf(x, x, nn); }
  float norm = sqrtf(nn);
  float f = nn / (1.f + nn) / (norm + 1e-8f);
#pragma unroll
  for (int o = 0; o < 16; o++) {
    float base = vprev ? vprev[t * 16 + o] : 0.f;
    vout[t * 16 + o] = base + f * sv[o];
  }
}

__global__ void squash_out_k(const float* __restrict__ s, float* __restrict__ out) {
  int t = threadIdx.x;   // 128
  float nn = 0.f;
#pragma unroll
  for (int o = 0; o < 16; o++) { float x = s[t * 16 + o]; nn = fmaf(x, x, nn); }
  float norm = sqrtf(nn);
  float f = nn / (1.f + nn) / (norm + 1e-8f);
  out[t] = f * norm;
}

extern "C" void kernel_launch(void* const* d_in, const int* in_sizes, int n_in,
                              void* d_out, int out_size, void* d_ws, size_t ws_size,
                              hipStream_t stream) {
  const float* x   = (const float*)d_in[0];
  const float* w1  = (const float*)d_in[1];
  const float* b1  = (const float*)d_in[2];
  const float* w2  = (const float*)d_in[3];
  const float* b2  = (const float*)d_in[4];
  const float* w3  = (const float*)d_in[5];
  const float* b3  = (const float*)d_in[6];
  const float* pcw = (const float*)d_in[7];
  const float* pcb = (const float*)d_in[8];
  const float* ecw = (const float*)d_in[9];
  float* out = (float*)d_out;

  float* ws = (float*)d_ws;
  size_t o = 0;
  float* hc   = ws + o; o += 3641344;   // conv1 out fp32 NCHW; later aliased as u
  float* yb   = ws + o; o += 3641344;   // conv2 out fp32 NCHW
  float* out3 = ws + o; o += 3641344;   // conv3 out
  ushort* hpc = (ushort*)(ws + o); o += 2568192;   // 16*19*264*64 bf16 NHWC padded
  ushort* wb  = (ushort*)(ws + o); o += 73728;     // 64*2304 bf16
  float* w3t  = ws + o; o += 8192;
  float* s0   = ws + o; o += 2048;
  float* s1   = ws + o; o += 2048;
  float* s2   = ws + o; o += 2048;
  float* v0   = ws + o; o += 2048;
  float* v1   = ws + o; o += 2048;
  float* ub   = hc;    // lifetime-disjoint alias (pc_k runs after conv3_k)

  hipMemsetAsync(hpc, 0, (size_t)16 * HPH * HPW2 * 64 * 2, stream);  // zero incl. pad
  hipMemsetAsync(s0, 0, 3 * 2048 * 4, stream);                       // s0|s1|s2 contiguous

  prep_w<<<576, 256, 0, stream>>>(w2, w3, wb, w3t);
  conv1_k<<<dim3(14, 16), 256, 0, stream>>>(x, w1, b1, hc);
  nhwc_k<<<dim3(4, 14, 16), 256, 0, stream>>>(hc, hpc);
  conv2_mfma<<<dim3(2, 14, 16), 256, 0, stream>>>(hpc, wb, b2, yb);
  conv3_k<<<dim3(4, 14, 16), 256, 0, stream>>>(hc, yb, w3t, b3, out3);
  pc_k<<<112, 256, 0, stream>>>(out3, pcw, pcb, ub);
  r0_k<<<889, 256, 0, stream>>>(ub, ecw, s0);
  squash_k<<<1, 128, 0, stream>>>(s0, 0.125f, nullptr, v0);  // c = 1/8 folded in
  rr_k<<<889, 256, 0, stream>>>(ub, ecw, v0, s1);
  squash_k<<<1, 128, 0, stream>>>(s1, 1.0f, v0, v1);         // v1 := v0 + squash(s1)  (b_log linearity)
  rr_k<<<889, 256, 0, stream>>>(ub, ecw, v1, s2);
  squash_out_k<<<1, 128, 0, stream>>>(s2, out);
}

// Round 6
// 495.603 us; speedup vs baseline: 1.1006x; 1.1006x over previous
//
#include <hip/hip_runtime.h>
#include <hip/hip_bf16.h>
#include <math.h>

#define BB 16
#define H1 14
#define W1 254
#define HPH 19
#define HPW2 264    // padded NHWC width (cols 0..263; data at 2..255)
#define NCAP 28448
#define FLATSZ 227584   // 64*14*254

typedef __attribute__((ext_vector_type(8))) short bf16x8;
typedef __attribute__((ext_vector_type(4))) float f32x4;

__device__ __forceinline__ ushort f2bf(float f) {
  __hip_bfloat16 h = __float2bfloat16(f);
  return *(ushort*)&h;
}

// ---------- weight prep: wb[co][tap*64+ci] bf16, w3t[c][co] fp32 ----------
__global__ __launch_bounds__(256) void prep_w(const float* __restrict__ w2, const float* __restrict__ w3,
                                              ushort* __restrict__ wb, float* __restrict__ w3t) {
  int idx = blockIdx.x * 256 + threadIdx.x;
  if (idx < 147456) {
    int co = idx / 2304; int rem = idx - co * 2304;
    int tap = rem >> 6; int ci = rem & 63;
    wb[idx] = f2bf(w2[(co * 64 + ci) * 36 + tap]);
  }
  if (idx < 8192) {
    int co = idx & 63; int c = idx >> 6;
    w3t[idx] = w3[co * 128 + c];
  }
}

// ---------- conv1: 1->64, 6x6, stride 2 -> compact fp32 hc[b][c][14][254] ----------
__global__ __launch_bounds__(256) void conv1_k(const float* __restrict__ x, const float* __restrict__ w1,
                                               const float* __restrict__ b1, float* __restrict__ hc) {
  const int i = blockIdx.x, b = blockIdx.y;
  __shared__ float xs[6 * 512];
  __shared__ float wsh[2304];
  __shared__ float bsh[64];
  const int t = threadIdx.x;
  for (int idx = t; idx < 6 * 512; idx += 256) {
    int r = idx >> 9, c = idx & 511;
    xs[idx] = x[((size_t)b * 32 + 2 * i + r) * 512 + c];
  }
  for (int idx = t; idx < 2304; idx += 256) wsh[idx] = w1[idx];
  if (t < 64) bsh[t] = b1[t];
  __syncthreads();
  if (t < 254) {
    for (int c = 0; c < 64; c++) {
      float acc = bsh[c];
#pragma unroll
      for (int p = 0; p < 6; p++)
#pragma unroll
        for (int q = 0; q < 6; q++)
          acc = fmaf(xs[p * 512 + 2 * t + q], wsh[c * 36 + p * 6 + q], acc);
      acc = fmaxf(acc, 0.f);
      hc[(((size_t)b * 64 + c) * H1 + i) * W1 + t] = acc;
    }
  }
}

// ---------- transpose hc (NCHW fp32) -> hpc (padded NHWC bf16) ----------
__global__ __launch_bounds__(256) void nhwc_k(const float* __restrict__ hc, ushort* __restrict__ hpc) {
  const int ct = blockIdx.x, i = blockIdx.y, b = blockIdx.z;
  const int c0 = ct * 64;
  __shared__ float ls[64 * 65];
  const int t = threadIdx.x;
  for (int idx = t; idx < 4096; idx += 256) {
    int ci = idx >> 6, cc = idx & 63;
    int c = c0 + cc;
    ls[ci * 65 + cc] = (c < W1) ? hc[(((size_t)b * 64 + ci) * H1 + i) * W1 + c] : 0.f;
  }
  __syncthreads();
  uint* outp = (uint*)hpc;
  for (int idx = t; idx < 2048; idx += 256) {
    int cc = idx >> 5, ci2 = idx & 31;
    int c = c0 + cc;
    if (c < W1) {
      float f0 = ls[(2 * ci2) * 65 + cc];
      float f1 = ls[(2 * ci2 + 1) * 65 + cc];
      uint pk = (uint)f2bf(f0) | ((uint)f2bf(f1) << 16);
      outp[(((size_t)b * HPH + 2 + i) * HPW2 + 2 + c) * 32 + ci2] = pk;
    }
  }
}

// ---------- conv2 implicit-GEMM bf16 MFMA (per-tap LDS double-buffer pipeline) ----------
__device__ __forceinline__ void stage_b(const ushort* __restrict__ wb, ushort* __restrict__ bbuf,
                                        int tap, int w, int l) {
#pragma unroll
  for (int r = 0; r < 2; r++) {
    int v = r * 256 + w * 64 + l;
    int co = v >> 3, s = v & 7;
    int g = s ^ (co & 7);                       // XOR swizzle: slot s holds k-group g
    const ushort* gp = wb + co * 2304 + tap * 64 + g * 8;
    ushort* lp = bbuf + (size_t)(r * 256 + w * 64) * 8;   // wave-uniform base; lane scatters +l*16B
    __builtin_amdgcn_global_load_lds((const uint*)gp, (uint*)lp, 16, 0, 0);
  }
}

__global__ __launch_bounds__(256, 1) void conv2_mfma(const ushort* __restrict__ hpc,
                                                     const ushort* __restrict__ wb,
                                                     const float* __restrict__ b2, float* __restrict__ y) {
  const int b = blockIdx.z, i = blockIdx.y, j0 = blockIdx.x * 128;
  const int t = threadIdx.x;
  const int w = t >> 6, l = t & 63;
  const int lr = l & 15, quad = l >> 4;

  __shared__ ushort bls[2][4096];   // [buf][co*64 + slot*8] bf16, swizzled

  f32x4 acc[2][4];
#pragma unroll
  for (int mt = 0; mt < 2; mt++)
#pragma unroll
    for (int nt = 0; nt < 4; nt++) acc[mt][nt] = (f32x4){0.f, 0.f, 0.f, 0.f};

  const ushort* abase = hpc + (((size_t)b * HPH + i) * HPW2 + (j0 + w * 32 + lr)) * 64 + quad * 8;

  bf16x8 a0[2][2], a1[2][2];   // [ch][mt] for current / next tap

#define ALOAD(dst, tap)                                                        \
  {                                                                            \
    const int p_ = (tap) / 6, q_ = (tap) % 6;                                  \
    const ushort* ap_ = abase + ((size_t)p_ * HPW2 + q_) * 64;                 \
    dst[0][0] = *(const bf16x8*)(ap_);                                         \
    dst[0][1] = *(const bf16x8*)(ap_ + 1024);                                  \
    dst[1][0] = *(const bf16x8*)(ap_ + 32);                                    \
    dst[1][1] = *(const bf16x8*)(ap_ + 32 + 1024);                             \
  }

#define COMPUTE(a, bp)                                                         \
  {                                                                            \
    _Pragma("unroll")                                                          \
    for (int ch = 0; ch < 2; ch++) {                                           \
      const int g2 = ch * 4 + quad;                                            \
      _Pragma("unroll")                                                        \
      for (int nt = 0; nt < 4; nt++) {                                         \
        const int co = nt * 16 + lr;                                           \
        bf16x8 bf = *(const bf16x8*)((bp) + co * 64 + ((g2 ^ (co & 7)) * 8));  \
        acc[0][nt] = __builtin_amdgcn_mfma_f32_16x16x32_bf16(a[ch][0], bf, acc[0][nt], 0, 0, 0); \
        acc[1][nt] = __builtin_amdgcn_mfma_f32_16x16x32_bf16(a[ch][1], bf, acc[1][nt], 0, 0, 0); \
      }                                                                        \
    }                                                                          \
  }

  stage_b(wb, &bls[0][0], 0, w, l);
  __syncthreads();                 // B(0) resident
  ALOAD(a0, 0);

  for (int tp = 0; tp < 36; tp += 2) {
    stage_b(wb, &bls[1][0], tp + 1, w, l);
    ALOAD(a1, tp + 1);
    COMPUTE(a0, &bls[0][0]);
    __syncthreads();
    if (tp + 2 < 36) {
      stage_b(wb, &bls[0][0], tp + 2, w, l);
      ALOAD(a0, tp + 2);
    }
    COMPUTE(a1, &bls[1][0]);
    __syncthreads();
  }

#pragma unroll
  for (int nt = 0; nt < 4; nt++) {
    const int co = nt * 16 + lr;
    const float bias = b2[co];
    float* yrow = y + (((size_t)b * 64 + co) * H1 + i) * W1;
#pragma unroll
    for (int mt = 0; mt < 2; mt++) {
      const int jb = j0 + w * 32 + mt * 16 + quad * 4;
#pragma unroll
      for (int r = 0; r < 4; r++) {
        int j = jb + r;
        if (j < W1) yrow[j] = fmaxf(acc[mt][nt][r] + bias, 0.f);
      }
    }
  }
#undef ALOAD
#undef COMPUTE
}

// ---------- conv3: 1x1, 128->64, over concat(hc, y); NO relu ----------
__global__ __launch_bounds__(256) void conv3_k(const float* __restrict__ hc, const float* __restrict__ y,
                                               const float* __restrict__ w3t, const float* __restrict__ b3,
                                               float* __restrict__ out3) {
  const int b = blockIdx.z, i = blockIdx.y, j0 = blockIdx.x * 64;
  __shared__ float cs[32][64];
  __shared__ float wsh[32][64];
  const int t = threadIdx.x;
  const int cog = t >> 4, jg = t & 15;
  float acc[4][4];
#pragma unroll
  for (int a = 0; a < 4; a++)
#pragma unroll
    for (int j = 0; j < 4; j++) acc[a][j] = 0.f;

  for (int ch = 0; ch < 4; ch++) {
    __syncthreads();
    for (int idx = t; idx < 2048; idx += 256) {
      int cl = idx >> 6; int j = j0 + (idx & 63);
      int c = ch * 32 + cl;
      float v = 0.f;
      if (j < W1) {
        if (c < 64) v = hc[(((size_t)b * 64 + c) * H1 + i) * W1 + j];
        else        v = y[(((size_t)b * 64 + (c - 64)) * H1 + i) * W1 + j];
      }
      cs[cl][idx & 63] = v;
    }
    for (int idx = t; idx < 2048; idx += 256)
      wsh[idx >> 6][idx & 63] = w3t[(ch * 32 + (idx >> 6)) * 64 + (idx & 63)];
    __syncthreads();
#pragma unroll
    for (int c = 0; c < 32; c++) {
      float4 xv = *(const float4*)&cs[c][jg * 4];
      float4 wv = *(const float4*)&wsh[c][cog * 4];
#pragma unroll
      for (int jj = 0; jj < 4; jj++) {
        float xx = (&xv.x)[jj];
        acc[0][jj] = fmaf(wv.x, xx, acc[0][jj]);
        acc[1][jj] = fmaf(wv.y, xx, acc[1][jj]);
        acc[2][jj] = fmaf(wv.z, xx, acc[2][jj]);
        acc[3][jj] = fmaf(wv.w, xx, acc[3][jj]);
      }
    }
  }
#pragma unroll
  for (int a = 0; a < 4; a++) {
    int co = cog * 4 + a;
    float bias = b3[co];
#pragma unroll
    for (int jj = 0; jj < 4; jj++) {
      int j = j0 + jg * 4 + jj;
      if (j < W1) out3[(((size_t)b * 64 + co) * H1 + i) * W1 + j] = acc[a][jj] + bias;
    }
  }
}

// ---------- pc: per-capsule 8x8 transform ----------
__global__ __launch_bounds__(256) void pc_k(const float* __restrict__ out3, const float* __restrict__ pcw,
                                            const float* __restrict__ pcb, float* __restrict__ u) {
  int n = blockIdx.x * 256 + threadIdx.x;
  if (n >= NCAP) return;
  float pw[64];
  const float4* pwp = (const float4*)(pcw + (size_t)n * 64);
#pragma unroll
  for (int k = 0; k < 16; k++) {
    float4 v = pwp[k];
    pw[4 * k] = v.x; pw[4 * k + 1] = v.y; pw[4 * k + 2] = v.z; pw[4 * k + 3] = v.w;
  }
  float pb[8];
  {
    const float4* pbp = (const float4*)(pcb + (size_t)n * 8);
    float4 a = pbp[0], b = pbp[1];
    pb[0] = a.x; pb[1] = a.y; pb[2] = a.z; pb[3] = a.w;
    pb[4] = b.x; pb[5] = b.y; pb[6] = b.z; pb[7] = b.w;
  }
  for (int b = 0; b < BB; b++) {
    const float4* uip = (const float4*)(out3 + (size_t)b * FLATSZ + (size_t)n * 8);
    float4 a = uip[0], c = uip[1];
    float ui[8] = {a.x, a.y, a.z, a.w, c.x, c.y, c.z, c.w};
    float uo[8];
#pragma unroll
    for (int o = 0; o < 8; o++) uo[o] = pb[o];
#pragma unroll
    for (int i2 = 0; i2 < 8; i2++)
#pragma unroll
      for (int o = 0; o < 8; o++) uo[o] = fmaf(ui[i2], pw[i2 * 8 + o], uo[o]);
    float4* up = (float4*)(u + ((size_t)b * NCAP + n) * 8);
    up[0] = make_float4(uo[0], uo[1], uo[2], uo[3]);
    up[1] = make_float4(uo[4], uo[5], uo[6], uo[7]);
  }
}

// ---------- routing v3: spill-proof ----------
// lane l <-> (e = l>>3, o-pair o0 = 2*(l&7)); ec_w[n] coalesced: lane l holds floats [16l,16l+16).
// Each wave: 8 n x 8 b (b-half selected by blockIdx.y). Live regs ~60 -> fits the 64-VGPR tier, no spill.
// u staged once per wave into LDS (coalesced), inner loop uses same-address ds_read broadcasts.
// MODE 0: s += uh (uniform c; 1/8 folded into squash). MODE 1: softmax-routed accumulate.
template <int MODE>
__global__ __launch_bounds__(256, 4) void route_k(const float* __restrict__ u, const float* __restrict__ ecw,
                                                  const float* __restrict__ v, float* __restrict__ sout) {
  const int t = threadIdx.x, l = t & 63, wv = t >> 6;
  const int b0 = blockIdx.y * 8;
  const int n0 = blockIdx.x * 32 + wv * 8;

  __shared__ float us[4][512];     // [wave][b*64 + nn*8 + i]
  __shared__ float red[4096];      // 16 KB transposed reduce
  __shared__ float vlds[1024];     // this b-half's v (MODE 1)

  if (MODE) {
    for (int idx = t; idx < 1024; idx += 256) vlds[idx] = v[b0 * 128 + idx];
    __syncthreads();
  }

  // stage this wave's u slab: 8 b x (8 n x 8 i = 64 floats)
#pragma unroll
  for (int bb = 0; bb < 8; bb++)
    us[wv][bb * 64 + l] = u[((size_t)(b0 + bb) * NCAP + n0) * 8 + l];
  // wave-private LDS: compiler inserts lgkmcnt wait before first ds_read; no barrier needed

  float sacc[16];
#pragma unroll
  for (int k = 0; k < 16; k++) sacc[k] = 0.f;

  for (int nn = 0; nn < 8; nn++) {
    const int n = n0 + nn;
    const float4* ep = (const float4*)(ecw + (size_t)n * 1024 + l * 16);
    float4 e0 = ep[0], e1 = ep[1], e2 = ep[2], e3 = ep[3];
    float ec[16] = {e0.x, e0.y, e0.z, e0.w, e1.x, e1.y, e1.z, e1.w,
                    e2.x, e2.y, e2.z, e2.w, e3.x, e3.y, e3.z, e3.w};
#pragma unroll
    for (int bb = 0; bb < 8; bb++) {
      const float4* up = (const float4*)&us[wv][bb * 64 + nn * 8];   // all lanes same addr: broadcast
      float4 ua = up[0], ubv = up[1];
      float uv[8] = {ua.x, ua.y, ua.z, ua.w, ubv.x, ubv.y, ubv.z, ubv.w};
      float h0 = 0.f, h1 = 0.f;
#pragma unroll
      for (int k = 0; k < 8; k++) { h0 = fmaf(ec[k], uv[k], h0); h1 = fmaf(ec[8 + k], uv[k], h1); }
      if (MODE == 0) {
        sacc[2 * bb] += h0; sacc[2 * bb + 1] += h1;
      } else {
        float2 vv = *(const float2*)&vlds[bb * 128 + 2 * l];
        float p = h0 * vv.x + h1 * vv.y;
        p += __shfl_xor(p, 1); p += __shfl_xor(p, 2); p += __shfl_xor(p, 4);   // dot over o
        float m = p;
        m = fmaxf(m, __shfl_xor(m, 8)); m = fmaxf(m, __shfl_xor(m, 16)); m = fmaxf(m, __shfl_xor(m, 32));
        float ex = __expf(p - m);
        float den = ex;
        den += __shfl_xor(den, 8); den += __shfl_xor(den, 16); den += __shfl_xor(den, 32);
        float cc = ex * __builtin_amdgcn_rcpf(den);
        sacc[2 * bb] = fmaf(cc, h0, sacc[2 * bb]);
        sacc[2 * bb + 1] = fmaf(cc, h1, sacc[2 * bb + 1]);
      }
    }
  }

  // transposed conflict-free block reduce -> one atomic per slot
#pragma unroll
  for (int k = 0; k < 16; k++) red[k * 256 + wv * 64 + l] = sacc[k];
  __syncthreads();
#pragma unroll
  for (int m = 0; m < 4; m++) {
    int slot = t + 256 * m;                       // slot = bl*128 + eo  (bl in [0,8))
    int bl = slot >> 7, eo = slot & 127;
    int k = 2 * bl + (eo & 1), l2 = eo >> 1;
    const float* r = red + k * 256 + l2;
    atomicAdd(&sout[(b0 + bl) * 128 + eo], r[0] + r[64] + r[128] + r[192]);
  }
}

// ---------- squash: vout = (vprev? vprev : 0) + squash(s*scale) ----------
__global__ void squash_k(const float* __restrict__ s, float scale, const float* __restrict__ vprev,
                         float* __restrict__ vout) {
  int t = threadIdx.x;   // 128 threads: (b,e)
  const float* sp = s + t * 16;
  float sv[16]; float nn = 0.f;
#pragma unroll
  for (int o = 0; o < 16; o++) { float x = sp[o] * scale; sv[o] = x; nn = fmaf(x, x, nn); }
  float norm = sqrtf(nn);
  float f = nn / (1.f + nn) / (norm + 1e-8f);
#pragma unroll
  for (int o = 0; o < 16; o++) {
    float base = vprev ? vprev[t * 16 + o] : 0.f;
    vout[t * 16 + o] = base + f * sv[o];
  }
}

__global__ void squash_out_k(const float* __restrict__ s, float* __restrict__ out) {
  int t = threadIdx.x;   // 128
  float nn = 0.f;
#pragma unroll
  for (int o = 0; o < 16; o++) { float x = s[t * 16 + o]; nn = fmaf(x, x, nn); }
  float norm = sqrtf(nn);
  float f = nn / (1.f + nn) / (norm + 1e-8f);
  out[t] = f * norm;
}

extern "C" void kernel_launch(void* const* d_in, const int* in_sizes, int n_in,
                              void* d_out, int out_size, void* d_ws, size_t ws_size,
                              hipStream_t stream) {
  const float* x   = (const float*)d_in[0];
  const float* w1  = (const float*)d_in[1];
  const float* b1  = (const float*)d_in[2];
  const float* w2  = (const float*)d_in[3];
  const float* b2  = (const float*)d_in[4];
  const float* w3  = (const float*)d_in[5];
  const float* b3  = (const float*)d_in[6];
  const float* pcw = (const float*)d_in[7];
  const float* pcb = (const float*)d_in[8];
  const float* ecw = (const float*)d_in[9];
  float* out = (float*)d_out;

  float* ws = (float*)d_ws;
  size_t o = 0;
  float* hc   = ws + o; o += 3641344;   // conv1 out fp32 NCHW; later aliased as u
  float* yb   = ws + o; o += 3641344;   // conv2 out fp32 NCHW
  float* out3 = ws + o; o += 3641344;   // conv3 out
  ushort* hpc = (ushort*)(ws + o); o += 2568192;   // 16*19*264*64 bf16 NHWC padded
  ushort* wb  = (ushort*)(ws + o); o += 73728;     // 64*2304 bf16
  float* w3t  = ws + o; o += 8192;
  float* s0   = ws + o; o += 2048;
  float* s1   = ws + o; o += 2048;
  float* s2   = ws + o; o += 2048;
  float* v0   = ws + o; o += 2048;
  float* v1   = ws + o; o += 2048;
  float* ub   = hc;    // lifetime-disjoint alias (pc_k runs after conv3_k)

  hipMemsetAsync(hpc, 0, (size_t)16 * HPH * HPW2 * 64 * 2, stream);  // zero incl. pad
  hipMemsetAsync(s0, 0, 3 * 2048 * 4, stream);                       // s0|s1|s2 contiguous

  prep_w<<<576, 256, 0, stream>>>(w2, w3, wb, w3t);
  conv1_k<<<dim3(14, 16), 256, 0, stream>>>(x, w1, b1, hc);
  nhwc_k<<<dim3(4, 14, 16), 256, 0, stream>>>(hc, hpc);
  conv2_mfma<<<dim3(2, 14, 16), 256, 0, stream>>>(hpc, wb, b2, yb);
  conv3_k<<<dim3(4, 14, 16), 256, 0, stream>>>(hc, yb, w3t, b3, out3);
  pc_k<<<112, 256, 0, stream>>>(out3, pcw, pcb, ub);
  route_k<0><<<dim3(889, 2), 256, 0, stream>>>(ub, ecw, nullptr, s0);
  squash_k<<<1, 128, 0, stream>>>(s0, 0.125f, nullptr, v0);  // c = 1/8 folded in
  route_k<1><<<dim3(889, 2), 256, 0, stream>>>(ub, ecw, v0, s1);
  squash_k<<<1, 128, 0, stream>>>(s1, 1.0f, v0, v1);         // v1 := v0 + squash(s1)  (b_log linearity)
  route_k<1><<<dim3(889, 2), 256, 0, stream>>>(ub, ecw, v1, s2);
  squash_out_k<<<1, 128, 0, stream>>>(s2, out);
}